// Round 1
// 4661.492 us; speedup vs baseline: 1.1086x; 1.1086x over previous
//
#include <hip/hip_runtime.h>

#define T_STEPS 1024
#define BATCH 32
#define HID 512
#define GATES 2048   // 4*HID
#define KDIM 512     // input size == HID

typedef __attribute__((ext_vector_type(8))) short short8;
typedef __attribute__((ext_vector_type(4))) float floatx4;

__device__ __forceinline__ unsigned short f2bf(float f) {
  union { float f; unsigned u; } v; v.f = f;
  return (unsigned short)((v.u + 0x7FFFu + ((v.u >> 16) & 1u)) >> 16);
}
__device__ __forceinline__ float fsigmoid(float x) {
  return 1.0f / (1.0f + __expf(-x));
}
__device__ __forceinline__ float ftanh(float x) {
  return 2.0f / (1.0f + __expf(-2.0f * x)) - 1.0f;
}

// ---------------------------------------------------------------------------
// init: zero the (h|seq) dword ping-pong buffers + flags with agent-scope
// stores so the persistent kernel's sc1 polls/loads never see stale poison.
// Zero == (h=0 | seq=0), which is exactly what step 0 consumers expect.
// ---------------------------------------------------------------------------
__global__ void init_kernel(unsigned* __restrict__ hbuf_u,   // 65536 dwords
                            unsigned* __restrict__ flags) {
  int idx = blockIdx.x * 256 + threadIdx.x;     // 65536 threads
  __hip_atomic_store(&hbuf_u[idx], 0u, __ATOMIC_RELAXED, __HIP_MEMORY_SCOPE_AGENT);
  if (idx < 128)
    __hip_atomic_store(&flags[idx], 0u, __ATOMIC_RELAXED, __HIP_MEMORY_SCOPE_AGENT);
}

// ---------------------------------------------------------------------------
// add bwd-direction buffer into out (split-store mode only)
// ---------------------------------------------------------------------------
__global__ void merge_kernel(float* __restrict__ out,
                             const float* __restrict__ add, int n4) {
  int i = blockIdx.x * 256 + threadIdx.x;
  int stride = gridDim.x * 256;
  for (; i < n4; i += stride) {
    float4 a = ((const float4*)add)[i];
    float4 o = ((float4*)out)[i];
    o.x += a.x; o.y += a.y; o.z += a.z; o.w += a.w;
    ((float4*)out)[i] = o;
  }
}

// ---------------------------------------------------------------------------
// Persistent bidirectional zoneout-LSTM. 64 blocks x 512 thr.
// blocks 0..31: forward, 32..63: backward. Block owns 16 hidden units
// (64 gate cols). W_hh / W_ih fragments live in registers.
//
// NEW h-exchange protocol (removes the publish store-ack RT from the
// critical path):
//  - h is transmitted as dwords (bf16 h | step_seq<<16), seq = s+1.
//  - producer: issue h dword stores (sc1) -> RAW s_barrier (rendezvous only,
//    NO vmcnt drain!) -> relaxed flag store. Flag RACES the data through
//    the fabric; arrival order is NOT assumed.
//  - consumer: after flag >= s, loads the (h|seq) dwords and VERIFIES
//    seq == s per dword; retries (rare) until all landed. seq is unique
//    per step (<= 1024 < 2^16), so no ABA; ping-pong x2 prevents overwrite
//    of in-flight reads (overwrite of buffer s&1 is flag-gated behind every
//    block finishing step s, which requires consumption complete).
// ---------------------------------------------------------------------------
__global__ __launch_bounds__(512) void lstm_persist(
    const float* __restrict__ X,           // [1024, 32, 512]
    const float* __restrict__ Wih,         // [2048, 512]
    const float* __restrict__ Whh,         // [2048, 512]
    const float* __restrict__ bih,         // [2048]
    const float* __restrict__ bhh,         // [2048]
    float* __restrict__ out,               // [1024*32*512]
    unsigned* __restrict__ hw,             // [2][2][32][512] dwords (h|seq)
    unsigned* __restrict__ flags,          // [2][64]
    float* __restrict__ obwd) {            // bwd out buffer (split) or null
  __shared__ unsigned short xs[32][520];   // staged x(t) bf16, +8 pad
  __shared__ unsigned short hs[32][520];   // staged h(s-1) bf16, +8 pad
  __shared__ float gp[2][32][64];          // gate partials per k-half

  const int tid = threadIdx.x;
  const int bid = blockIdx.x;
  const int dir = bid >> 5;
  const int bsl = bid & 31;
  const int u0 = bsl * 16;

  unsigned* myflags = flags + dir * 64;
  unsigned* hwD = hw + dir * 2 * (BATCH * HID);   // per-direction dword region

  const int w = tid >> 6, lane = tid & 63;
  const int kh = w >> 2;   // k-half: [kh*256, kh*256+256)
  const int nt = w & 3;    // gate index (16-col n-tile)
  const int colx = lane & 15, q = lane >> 4;

  // Preload this wave's B-fragments into registers: gate nt, unit u0+colx.
  short8 bwh[8], bwx[8];
  {
    const size_t roff = (size_t)(nt * HID + u0 + colx) * KDIM + kh * 256 + q * 8;
    const float* wrh = Whh + roff;
    const float* wrx = Wih + roff;
#pragma unroll
    for (int ks = 0; ks < 8; ++ks) {
      float4 h0 = *(const float4*)(wrh + ks * 32);
      float4 h1 = *(const float4*)(wrh + ks * 32 + 4);
      union { unsigned short u[8]; short8 v; } pk;
      pk.u[0] = f2bf(h0.x); pk.u[1] = f2bf(h0.y); pk.u[2] = f2bf(h0.z); pk.u[3] = f2bf(h0.w);
      pk.u[4] = f2bf(h1.x); pk.u[5] = f2bf(h1.y); pk.u[6] = f2bf(h1.z); pk.u[7] = f2bf(h1.w);
      bwh[ks] = pk.v;
      float4 x0 = *(const float4*)(wrx + ks * 32);
      float4 x1 = *(const float4*)(wrx + ks * 32 + 4);
      union { unsigned short u[8]; short8 v; } px;
      px.u[0] = f2bf(x0.x); px.u[1] = f2bf(x0.y); px.u[2] = f2bf(x0.z); px.u[3] = f2bf(x0.w);
      px.u[4] = f2bf(x1.x); px.u[5] = f2bf(x1.y); px.u[6] = f2bf(x1.z); px.u[7] = f2bf(x1.w);
      bwx[ks] = px.v;
    }
  }

  // Per-thread pointwise assignment: batch b, unit u (global col u0+u)
  const int b = tid >> 4, u = tid & 15;
  const float bias_i = bih[0 * HID + u0 + u] + bhh[0 * HID + u0 + u];
  const float bias_f = bih[1 * HID + u0 + u] + bhh[1 * HID + u0 + u];
  const float bias_g = bih[2 * HID + u0 + u] + bhh[2 * HID + u0 + u];
  const float bias_o = bih[3 * HID + u0 + u] + bhh[3 * HID + u0 + u];

  float c_st = 0.f, h_prev = 0.f;

  float* odst = nullptr;
  if (obwd) odst = dir ? obwd : out;   // split-store mode

  // ---- prologue: prefetch x(t0) into registers ----
  float4 xr[8];
  {
    const int t0 = dir ? (T_STEPS - 1) : 0;
    const float* xt = X + (size_t)t0 * BATCH * KDIM;
#pragma unroll
    for (int r = 0; r < 8; ++r) {
      int idx = tid + r * 512;
      xr[r] = *(const float4*)(xt + (size_t)(idx >> 7) * KDIM + (idx & 127) * 4);
    }
  }

  for (int s = 0; s < T_STEPS; ++s) {
    const int t = dir ? (T_STEPS - 1 - s) : s;

    // ---- convert prefetched x(t) -> LDS bf16 ----
#pragma unroll
    for (int r = 0; r < 8; ++r) {
      int idx = tid + r * 512;
      int row = idx >> 7;
      int c4 = (idx & 127) * 4;
      union { unsigned short u[4]; uint2 v; } p;
      p.u[0] = f2bf(xr[r].x); p.u[1] = f2bf(xr[r].y);
      p.u[2] = f2bf(xr[r].z); p.u[3] = f2bf(xr[r].w);
      *(uint2*)&xs[row][c4] = p.v;
    }
    __syncthreads();   // B1

    // ---- x-projection MFMAs (independent of h) ----
    floatx4 acc0 = {0.f, 0.f, 0.f, 0.f}, acc1 = {0.f, 0.f, 0.f, 0.f};
    {
      const unsigned short* a0p = &xs[colx][kh * 256 + q * 8];
      const unsigned short* a1p = &xs[16 + colx][kh * 256 + q * 8];
#pragma unroll
      for (int ks = 0; ks < 8; ++ks) {
        short8 a0 = *(const short8*)(a0p + ks * 32);
        short8 a1 = *(const short8*)(a1p + ks * 32);
        acc0 = __builtin_amdgcn_mfma_f32_16x16x32_bf16(a0, bwx[ks], acc0, 0, 0, 0);
        acc1 = __builtin_amdgcn_mfma_f32_16x16x32_bf16(a1, bwx[ks], acc1, 0, 0, 0);
      }
    }

    // ---- issue x(t+1) prefetch; completes during the flag wait ----
    {
      const int sn = (s + 1 < T_STEPS) ? (s + 1) : s;
      const int tn = dir ? (T_STEPS - 1 - sn) : sn;
      const float* xt = X + (size_t)tn * BATCH * KDIM;
#pragma unroll
      for (int r = 0; r < 8; ++r) {
        int idx = tid + r * 512;
        xr[r] = *(const float4*)(xt + (size_t)(idx >> 7) * KDIM + (idx & 127) * 4);
      }
    }

    // ---- wait: all blocks of this direction issued step s-1 publishes ----
    if (tid < 32) {
      const unsigned target = (unsigned)s;
      while (__hip_atomic_load(&myflags[tid], __ATOMIC_RELAXED, __HIP_MEMORY_SCOPE_AGENT) < target)
        __builtin_amdgcn_s_sleep(1);
    }
    __syncthreads();   // B2

    // ---- stage h(s-1) -> LDS with seq verification ----
    // Each thread: 16 qwords (= 32 (h|seq) dwords), verify seq==s, retry if
    // any producer store hasn't landed yet (flag raced the data), then pack
    // 2 bf16 per dword into hs.
    {
      const unsigned long long* hq =
          (const unsigned long long*)(hwD + (s & 1) * (BATCH * HID));
      const unsigned long long rep = ((unsigned long long)(unsigned)s << 16) |
                                     ((unsigned long long)(unsigned)s << 48);
      unsigned long long v[16];
      for (;;) {
#pragma unroll
        for (int r = 0; r < 16; ++r)
          v[r] = __hip_atomic_load(&hq[tid + r * 512], __ATOMIC_RELAXED,
                                   __HIP_MEMORY_SCOPE_AGENT);
        unsigned long long bad = 0;
#pragma unroll
        for (int r = 0; r < 16; ++r) bad |= (v[r] ^ rep);
        if (!(bad & 0xFFFF0000FFFF0000ULL)) break;   // all seqs fresh
        __builtin_amdgcn_s_sleep(1);                 // rare straggler store
      }
#pragma unroll
      for (int r = 0; r < 16; ++r) {
        int g = tid + r * 512;                       // qword index 0..8191
        unsigned packed = (unsigned)(v[r] & 0xFFFFu) |
                          ((unsigned)(v[r] >> 32) << 16);
        *(unsigned*)&hs[g >> 8][(g & 255) * 2] = packed;
      }
    }
    __syncthreads();   // B3

    // ---- h-projection MFMAs ----
    {
      const unsigned short* a0p = &hs[colx][kh * 256 + q * 8];
      const unsigned short* a1p = &hs[16 + colx][kh * 256 + q * 8];
#pragma unroll
      for (int ks = 0; ks < 8; ++ks) {
        short8 a0 = *(const short8*)(a0p + ks * 32);
        short8 a1 = *(const short8*)(a1p + ks * 32);
        acc0 = __builtin_amdgcn_mfma_f32_16x16x32_bf16(a0, bwh[ks], acc0, 0, 0, 0);
        acc1 = __builtin_amdgcn_mfma_f32_16x16x32_bf16(a1, bwh[ks], acc1, 0, 0, 0);
      }
    }
#pragma unroll
    for (int r = 0; r < 4; ++r) {
      gp[kh][q * 4 + r][nt * 16 + colx] = acc0[r];
      gp[kh][16 + q * 4 + r][nt * 16 + colx] = acc1[r];
    }
    __syncthreads();   // B4

    // ---- pointwise LSTM cell + zoneout for (b, u) ----
    float gi = gp[0][b][u]      + gp[1][b][u]      + bias_i;
    float gf = gp[0][b][16 + u] + gp[1][b][16 + u] + bias_f;
    float gg = gp[0][b][32 + u] + gp[1][b][32 + u] + bias_g;
    float go = gp[0][b][48 + u] + gp[1][b][48 + u] + bias_o;
    float si = fsigmoid(gi);
    float sf = fsigmoid(gf);
    float tg = ftanh(gg);
    float so = fsigmoid(go);
    float c_new = sf * c_st + si * tg;
    float h_new = so * ftanh(c_new);
    c_st = 0.9f * c_new + 0.1f * c_st;
    float h = 0.9f * h_new + 0.1f * h_prev;
    h_prev = h;

    // ---- publish h: per-thread (h|seq) dword, sc1, NO drain before flag ----
    {
      unsigned D = (unsigned)f2bf(h) | ((unsigned)(s + 1) << 16);
      unsigned* hop = hwD + ((s + 1) & 1) * (BATCH * HID);
      __hip_atomic_store(&hop[b * HID + u0 + u], D,
                         __ATOMIC_RELAXED, __HIP_MEMORY_SCOPE_AGENT);
    }
    // B5: RAW rendezvous barrier. All threads have ISSUED their h stores
    // (program order per thread), so the flag may fire now; consumers
    // verify seq and retry if the flag beats any store to the LLC.
    asm volatile("s_barrier" ::: "memory");
    if (tid == 0)
      __hip_atomic_store(&myflags[bsl], (unsigned)(s + 1),
                         __ATOMIC_RELAXED, __HIP_MEMORY_SCOPE_AGENT);

    // off the critical path: output write
    {
      size_t oidx = (size_t)(t * BATCH + b) * HID + u0 + u;
      if (odst) __builtin_nontemporal_store(h, &odst[oidx]);
      else atomicAdd(out + oidx, h);   // fallback: tiny workspace
    }
  }
}

// ---------------------------------------------------------------------------
extern "C" void kernel_launch(void* const* d_in, const int* in_sizes, int n_in,
                              void* d_out, int out_size, void* d_ws, size_t ws_size,
                              hipStream_t stream) {
  const float* X   = (const float*)d_in[0];
  const float* Wih = (const float*)d_in[1];
  const float* Whh = (const float*)d_in[2];
  const float* bih = (const float*)d_in[3];
  const float* bhh = (const float*)d_in[4];
  float* out = (float*)d_out;

  // workspace layout:
  //   [0, 256KB):    hw   = [2 dir][2 buf][32][512] (h|seq) dwords (256 KB)
  //                  flags = 128 u32 right after hw
  //   [1MB, 1MB+64MB): bwd-direction output buffer (split-store mode)
  unsigned* hw = (unsigned*)d_ws;                     // 65536 dwords
  unsigned* flags = hw + 2 * 2 * BATCH * HID;         // 128 u32

  float* obwd = nullptr;
  const size_t need_split = (size_t)(1u << 20) +
                            (size_t)T_STEPS * BATCH * HID * sizeof(float);
  if (ws_size >= need_split)
    obwd = (float*)((char*)d_ws + (1u << 20));

  if (!obwd)   // fallback: atomicAdd accumulation needs zeroed out
    hipMemsetAsync(d_out, 0, (size_t)out_size * sizeof(float), stream);

  hipLaunchKernelGGL(init_kernel, dim3(256), dim3(256), 0, stream, hw, flags);
  hipLaunchKernelGGL(lstm_persist, dim3(64), dim3(512), 0, stream,
                     X, Wih, Whh, bih, bhh, out, hw, flags, obwd);
  if (obwd)
    hipLaunchKernelGGL(merge_kernel, dim3(2048), dim3(256), 0, stream,
                       out, obwd, (T_STEPS * BATCH * HID) / 4);
}

// Round 2
// 4353.526 us; speedup vs baseline: 1.1870x; 1.0707x over previous
//
#include <hip/hip_runtime.h>

#define T_STEPS 1024
#define BATCH 32
#define HID 512
#define GATES 2048   // 4*HID
#define KDIM 512     // input size == HID

typedef __attribute__((ext_vector_type(8))) short short8;
typedef __attribute__((ext_vector_type(4))) float floatx4;

__device__ __forceinline__ unsigned short f2bf(float f) {
  union { float f; unsigned u; } v; v.f = f;
  return (unsigned short)((v.u + 0x7FFFu + ((v.u >> 16) & 1u)) >> 16);
}
__device__ __forceinline__ float fsigmoid(float x) {
  return 1.0f / (1.0f + __expf(-x));
}
__device__ __forceinline__ float ftanh(float x) {
  return 2.0f / (1.0f + __expf(-2.0f * x)) - 1.0f;
}

// ---------------------------------------------------------------------------
// init: zero the (h|seq) dword ping-pong buffers with agent-scope stores so
// the persistent kernel's sc1 polls never see stale poison.
// Zero == (h=0 | seq=0), which is exactly what step-0 consumers poll for.
// ---------------------------------------------------------------------------
__global__ void init_kernel(unsigned* __restrict__ hbuf_u) {  // 65536 dwords
  int idx = blockIdx.x * 256 + threadIdx.x;     // 65536 threads
  __hip_atomic_store(&hbuf_u[idx], 0u, __ATOMIC_RELAXED, __HIP_MEMORY_SCOPE_AGENT);
}

// ---------------------------------------------------------------------------
// add bwd-direction buffer into out (split-store mode only)
// ---------------------------------------------------------------------------
__global__ void merge_kernel(float* __restrict__ out,
                             const float* __restrict__ add, int n4) {
  int i = blockIdx.x * 256 + threadIdx.x;
  int stride = gridDim.x * 256;
  for (; i < n4; i += stride) {
    float4 a = ((const float4*)add)[i];
    float4 o = ((float4*)out)[i];
    o.x += a.x; o.y += a.y; o.z += a.z; o.w += a.w;
    ((float4*)out)[i] = o;
  }
}

// ---------------------------------------------------------------------------
// Persistent bidirectional zoneout-LSTM. 64 blocks x 512 thr.
// blocks 0..31: forward, 32..63: backward. Block owns 16 hidden units
// (64 gate cols). W_hh / W_ih fragments live in registers.
//
// h-exchange protocol (flagless, self-validating data):
//  - h is transmitted as dwords (bf16 h | step_seq<<16), seq = s+1, via
//    agent-scope (sc1) relaxed stores. No flags, no fences, no barriers
//    after publish.
//  - consumer at step s polls buffer s&1 directly: each thread loads its
//    16 qwords and checks every embedded seq == s; retries until fresh.
//    The successful iteration's loads ARE the staging loads.
//  - seq is unique per step (<= 1025 < 2^16) -> no ABA. Ping-pong x2 is
//    overwrite-safe by construction: publishing step s+1 (overwriting
//    buffer s&1) requires having polled ALL blocks' seq-(s+1) data, which
//    (program order) is after those blocks completed their buffer-s&1
//    reads into registers.
// ---------------------------------------------------------------------------
__global__ __launch_bounds__(512) void lstm_persist(
    const float* __restrict__ X,           // [1024, 32, 512]
    const float* __restrict__ Wih,         // [2048, 512]
    const float* __restrict__ Whh,         // [2048, 512]
    const float* __restrict__ bih,         // [2048]
    const float* __restrict__ bhh,         // [2048]
    float* __restrict__ out,               // [1024*32*512]
    unsigned* __restrict__ hw,             // [2][2][32][512] dwords (h|seq)
    float* __restrict__ obwd) {            // bwd out buffer (split) or null
  __shared__ unsigned short xs[32][520];   // staged x(t) bf16, +8 pad
  __shared__ unsigned short hs[32][520];   // staged h(s-1) bf16, +8 pad
  __shared__ float gp[2][32][64];          // gate partials per k-half

  const int tid = threadIdx.x;
  const int bid = blockIdx.x;
  const int dir = bid >> 5;
  const int bsl = bid & 31;
  const int u0 = bsl * 16;

  unsigned* hwD = hw + dir * 2 * (BATCH * HID);   // per-direction dword region

  const int w = tid >> 6, lane = tid & 63;
  const int kh = w >> 2;   // k-half: [kh*256, kh*256+256)
  const int nt = w & 3;    // gate index (16-col n-tile)
  const int colx = lane & 15, q = lane >> 4;

  // Preload this wave's B-fragments into registers: gate nt, unit u0+colx.
  short8 bwh[8], bwx[8];
  {
    const size_t roff = (size_t)(nt * HID + u0 + colx) * KDIM + kh * 256 + q * 8;
    const float* wrh = Whh + roff;
    const float* wrx = Wih + roff;
#pragma unroll
    for (int ks = 0; ks < 8; ++ks) {
      float4 h0 = *(const float4*)(wrh + ks * 32);
      float4 h1 = *(const float4*)(wrh + ks * 32 + 4);
      union { unsigned short u[8]; short8 v; } pk;
      pk.u[0] = f2bf(h0.x); pk.u[1] = f2bf(h0.y); pk.u[2] = f2bf(h0.z); pk.u[3] = f2bf(h0.w);
      pk.u[4] = f2bf(h1.x); pk.u[5] = f2bf(h1.y); pk.u[6] = f2bf(h1.z); pk.u[7] = f2bf(h1.w);
      bwh[ks] = pk.v;
      float4 x0 = *(const float4*)(wrx + ks * 32);
      float4 x1 = *(const float4*)(wrx + ks * 32 + 4);
      union { unsigned short u[8]; short8 v; } px;
      px.u[0] = f2bf(x0.x); px.u[1] = f2bf(x0.y); px.u[2] = f2bf(x0.z); px.u[3] = f2bf(x0.w);
      px.u[4] = f2bf(x1.x); px.u[5] = f2bf(x1.y); px.u[6] = f2bf(x1.z); px.u[7] = f2bf(x1.w);
      bwx[ks] = px.v;
    }
  }

  // Per-thread pointwise assignment: batch b, unit u (global col u0+u)
  const int b = tid >> 4, u = tid & 15;
  const float bias_i = bih[0 * HID + u0 + u] + bhh[0 * HID + u0 + u];
  const float bias_f = bih[1 * HID + u0 + u] + bhh[1 * HID + u0 + u];
  const float bias_g = bih[2 * HID + u0 + u] + bhh[2 * HID + u0 + u];
  const float bias_o = bih[3 * HID + u0 + u] + bhh[3 * HID + u0 + u];

  float c_st = 0.f, h_prev = 0.f;

  float* odst = nullptr;
  if (obwd) odst = dir ? obwd : out;   // split-store mode

  // ---- prologue: prefetch x(t0) into registers ----
  float4 xr[8];
  {
    const int t0 = dir ? (T_STEPS - 1) : 0;
    const float* xt = X + (size_t)t0 * BATCH * KDIM;
#pragma unroll
    for (int r = 0; r < 8; ++r) {
      int idx = tid + r * 512;
      xr[r] = *(const float4*)(xt + (size_t)(idx >> 7) * KDIM + (idx & 127) * 4);
    }
  }

  for (int s = 0; s < T_STEPS; ++s) {
    const int t = dir ? (T_STEPS - 1 - s) : s;

    // ---- convert prefetched x(t) -> LDS bf16 ----
#pragma unroll
    for (int r = 0; r < 8; ++r) {
      int idx = tid + r * 512;
      int row = idx >> 7;
      int c4 = (idx & 127) * 4;
      union { unsigned short u[4]; uint2 v; } p;
      p.u[0] = f2bf(xr[r].x); p.u[1] = f2bf(xr[r].y);
      p.u[2] = f2bf(xr[r].z); p.u[3] = f2bf(xr[r].w);
      *(uint2*)&xs[row][c4] = p.v;
    }
    __syncthreads();   // B1

    // ---- x-projection MFMAs (independent of h) ----
    floatx4 acc0 = {0.f, 0.f, 0.f, 0.f}, acc1 = {0.f, 0.f, 0.f, 0.f};
    {
      const unsigned short* a0p = &xs[colx][kh * 256 + q * 8];
      const unsigned short* a1p = &xs[16 + colx][kh * 256 + q * 8];
#pragma unroll
      for (int ks = 0; ks < 8; ++ks) {
        short8 a0 = *(const short8*)(a0p + ks * 32);
        short8 a1 = *(const short8*)(a1p + ks * 32);
        acc0 = __builtin_amdgcn_mfma_f32_16x16x32_bf16(a0, bwx[ks], acc0, 0, 0, 0);
        acc1 = __builtin_amdgcn_mfma_f32_16x16x32_bf16(a1, bwx[ks], acc1, 0, 0, 0);
      }
    }

    // ---- issue x(t+1) prefetch; completes during the data poll ----
    {
      const int sn = (s + 1 < T_STEPS) ? (s + 1) : s;
      const int tn = dir ? (T_STEPS - 1 - sn) : sn;
      const float* xt = X + (size_t)tn * BATCH * KDIM;
#pragma unroll
      for (int r = 0; r < 8; ++r) {
        int idx = tid + r * 512;
        xr[r] = *(const float4*)(xt + (size_t)(idx >> 7) * KDIM + (idx & 127) * 4);
      }
    }

    // ---- wait + stage: poll h(s-1) data directly (self-validating seq) ----
    // Each thread: 16 qwords (= 32 (h|seq) dwords); all seqs must equal s.
    // Successful iteration's loads double as the staging loads.
    {
      const unsigned long long* hq =
          (const unsigned long long*)(hwD + (s & 1) * (BATCH * HID));
      const unsigned long long rep = ((unsigned long long)(unsigned)s << 16) |
                                     ((unsigned long long)(unsigned)s << 48);
      unsigned long long v[16];
      for (;;) {
#pragma unroll
        for (int r = 0; r < 16; ++r)
          v[r] = __hip_atomic_load(&hq[tid + r * 512], __ATOMIC_RELAXED,
                                   __HIP_MEMORY_SCOPE_AGENT);
        unsigned long long bad = 0;
#pragma unroll
        for (int r = 0; r < 16; ++r) bad |= (v[r] ^ rep);
        if (!(bad & 0xFFFF0000FFFF0000ULL)) break;   // all seqs fresh
        __builtin_amdgcn_s_sleep(1);                 // stragglers in flight
      }
#pragma unroll
      for (int r = 0; r < 16; ++r) {
        int g = tid + r * 512;                       // qword index 0..8191
        unsigned packed = (unsigned)(v[r] & 0xFFFFu) |
                          ((unsigned)(v[r] >> 32) << 16);
        *(unsigned*)&hs[g >> 8][(g & 255) * 2] = packed;
      }
    }
    __syncthreads();   // B2 (stage complete before h-MFMA reads)

    // ---- h-projection MFMAs ----
    {
      const unsigned short* a0p = &hs[colx][kh * 256 + q * 8];
      const unsigned short* a1p = &hs[16 + colx][kh * 256 + q * 8];
#pragma unroll
      for (int ks = 0; ks < 8; ++ks) {
        short8 a0 = *(const short8*)(a0p + ks * 32);
        short8 a1 = *(const short8*)(a1p + ks * 32);
        acc0 = __builtin_amdgcn_mfma_f32_16x16x32_bf16(a0, bwh[ks], acc0, 0, 0, 0);
        acc1 = __builtin_amdgcn_mfma_f32_16x16x32_bf16(a1, bwh[ks], acc1, 0, 0, 0);
      }
    }
#pragma unroll
    for (int r = 0; r < 4; ++r) {
      gp[kh][q * 4 + r][nt * 16 + colx] = acc0[r];
      gp[kh][16 + q * 4 + r][nt * 16 + colx] = acc1[r];
    }
    __syncthreads();   // B3

    // ---- pointwise LSTM cell + zoneout for (b, u) ----
    float gi = gp[0][b][u]      + gp[1][b][u]      + bias_i;
    float gf = gp[0][b][16 + u] + gp[1][b][16 + u] + bias_f;
    float gg = gp[0][b][32 + u] + gp[1][b][32 + u] + bias_g;
    float go = gp[0][b][48 + u] + gp[1][b][48 + u] + bias_o;
    float si = fsigmoid(gi);
    float sf = fsigmoid(gf);
    float tg = ftanh(gg);
    float so = fsigmoid(go);
    float c_new = sf * c_st + si * tg;
    float h_new = so * ftanh(c_new);
    c_st = 0.9f * c_new + 0.1f * c_st;
    float h = 0.9f * h_new + 0.1f * h_prev;
    h_prev = h;

    // ---- publish h: per-thread (h|seq) dword, sc1; no barrier, no flag ----
    {
      unsigned D = (unsigned)f2bf(h) | ((unsigned)(s + 1) << 16);
      unsigned* hop = hwD + ((s + 1) & 1) * (BATCH * HID);
      __hip_atomic_store(&hop[b * HID + u0 + u], D,
                         __ATOMIC_RELAXED, __HIP_MEMORY_SCOPE_AGENT);
    }

    // off the critical path: output write
    {
      size_t oidx = (size_t)(t * BATCH + b) * HID + u0 + u;
      if (odst) __builtin_nontemporal_store(h, &odst[oidx]);
      else atomicAdd(out + oidx, h);   // fallback: tiny workspace
    }
  }
}

// ---------------------------------------------------------------------------
extern "C" void kernel_launch(void* const* d_in, const int* in_sizes, int n_in,
                              void* d_out, int out_size, void* d_ws, size_t ws_size,
                              hipStream_t stream) {
  const float* X   = (const float*)d_in[0];
  const float* Wih = (const float*)d_in[1];
  const float* Whh = (const float*)d_in[2];
  const float* bih = (const float*)d_in[3];
  const float* bhh = (const float*)d_in[4];
  float* out = (float*)d_out;

  // workspace layout:
  //   [0, 256KB):      hw = [2 dir][2 buf][32][512] (h|seq) dwords (256 KB)
  //   [1MB, 1MB+64MB): bwd-direction output buffer (split-store mode)
  unsigned* hw = (unsigned*)d_ws;                     // 65536 dwords

  float* obwd = nullptr;
  const size_t need_split = (size_t)(1u << 20) +
                            (size_t)T_STEPS * BATCH * HID * sizeof(float);
  if (ws_size >= need_split)
    obwd = (float*)((char*)d_ws + (1u << 20));

  if (!obwd)   // fallback: atomicAdd accumulation needs zeroed out
    hipMemsetAsync(d_out, 0, (size_t)out_size * sizeof(float), stream);

  hipLaunchKernelGGL(init_kernel, dim3(256), dim3(256), 0, stream, hw);
  hipLaunchKernelGGL(lstm_persist, dim3(64), dim3(512), 0, stream,
                     X, Wih, Whh, bih, bhh, out, hw, obwd);
  if (obwd)
    hipLaunchKernelGGL(merge_kernel, dim3(2048), dim3(256), 0, stream,
                       out, obwd, (T_STEPS * BATCH * HID) / 4);
}